// Round 3
// baseline (53.946 us; speedup 1.0000x reference)
//
#include <hip/hip_runtime.h>
#include <hip/hip_cooperative_groups.h>
#include <math.h>

namespace cg = cooperative_groups;

#define BATCH 128
#define GRID_N 10000
#define DIM 32
#define MCOLS 100
#define NCHUNK 8      // g-chunks in phase A
#define GCHUNK 1250   // g's per chunk
#define NBLK 256

// ---------------------------------------------------------------------------
// Fused SOM step, cooperative launch (256 blocks x 256 threads, 1 block/CU).
// Phase A: partial BMU (32 b-groups of 4 rows x 8 g-chunks). grid.sync().
// Phase C (blocks 0..156): per-block argmin finalize (L2-hot 8KB partials,
// agent-scope loads for cross-XCD visibility) + weight update; block 0 also
// writes bmu_loc and mean(mindist).
// ---------------------------------------------------------------------------
__global__ __launch_bounds__(256) void som_fused(
    const float* __restrict__ x, const float* __restrict__ c,
    const int* __restrict__ loc, const float* __restrict__ lrp,
    float* __restrict__ out, float* pmin, int* pidx)
{
    const int t   = threadIdx.x;
    const int blk = blockIdx.x;

    __shared__ float sm[4][4];
    __shared__ int   si[4][4];
    __shared__ float bi_s[BATCH], bj_s[BATCH];
    __shared__ float red[4][64][33];
    __shared__ float partial[2];

    // ---------------- Phase A: partial BMU ----------------
    {
        const int bg    = blk >> 3;      // 0..31
        const int chunk = blk & 7;       // 0..7
        const int b0    = bg * 4;

        float xr[4][DIM];
#pragma unroll
        for (int i = 0; i < 4; ++i)
#pragma unroll
            for (int d = 0; d < DIM; ++d)
                xr[i][d] = x[(b0 + i) * DIM + d];

        const int gstart = chunk * GCHUNK;
        float best[4] = {3.4e38f, 3.4e38f, 3.4e38f, 3.4e38f};
        int   idx[4]  = {0, 0, 0, 0};

        for (int g = gstart + t; g < gstart + GCHUNK; g += 256) {
            const float4* cr = (const float4*)(c + (size_t)g * DIM);
            float d2[4] = {0.f, 0.f, 0.f, 0.f};
#pragma unroll
            for (int k = 0; k < 8; ++k) {
                float4 cv = cr[k];
#pragma unroll
                for (int i = 0; i < 4; ++i) {
                    float a;
                    a = xr[i][4*k+0] - cv.x; d2[i] = fmaf(a, a, d2[i]);
                    a = xr[i][4*k+1] - cv.y; d2[i] = fmaf(a, a, d2[i]);
                    a = xr[i][4*k+2] - cv.z; d2[i] = fmaf(a, a, d2[i]);
                    a = xr[i][4*k+3] - cv.w; d2[i] = fmaf(a, a, d2[i]);
                }
            }
#pragma unroll
            for (int i = 0; i < 4; ++i)
                if (d2[i] < best[i]) { best[i] = d2[i]; idx[i] = g; }  // strict <
        }

#pragma unroll
        for (int m = 1; m < 64; m <<= 1) {
#pragma unroll
            for (int i = 0; i < 4; ++i) {
                float o  = __shfl_xor(best[i], m);
                int   oi = __shfl_xor(idx[i], m);
                if (o < best[i] || (o == best[i] && oi < idx[i])) { best[i] = o; idx[i] = oi; }
            }
        }

        const int wave = t >> 6, lane = t & 63;
        if (lane == 0) {
#pragma unroll
            for (int i = 0; i < 4; ++i) { sm[i][wave] = best[i]; si[i][wave] = idx[i]; }
        }
        __syncthreads();
        if (t < 4) {
            float bb = sm[t][0]; int bi = si[t][0];
#pragma unroll
            for (int w = 1; w < 4; ++w)
                if (sm[t][w] < bb || (sm[t][w] == bb && si[t][w] < bi)) { bb = sm[t][w]; bi = si[t][w]; }
            __hip_atomic_store(&pmin[(b0 + t) * NCHUNK + chunk], bb,
                               __ATOMIC_RELAXED, __HIP_MEMORY_SCOPE_AGENT);
            __hip_atomic_store(&pidx[(b0 + t) * NCHUNK + chunk], bi,
                               __ATOMIC_RELAXED, __HIP_MEMORY_SCOPE_AGENT);
        }
    }

    cg::this_grid().sync();

    if (blk >= 157) return;

    // ---------------- Phase C: finalize + update ----------------
    float msum = 0.f;
    if (t < BATCH) {
        float best = __hip_atomic_load(&pmin[t * NCHUNK], __ATOMIC_RELAXED, __HIP_MEMORY_SCOPE_AGENT);
        int   bi   = __hip_atomic_load(&pidx[t * NCHUNK], __ATOMIC_RELAXED, __HIP_MEMORY_SCOPE_AGENT);
#pragma unroll
        for (int k = 1; k < NCHUNK; ++k) {
            float v = __hip_atomic_load(&pmin[t * NCHUNK + k], __ATOMIC_RELAXED, __HIP_MEMORY_SCOPE_AGENT);
            int   i = __hip_atomic_load(&pidx[t * NCHUNK + k], __ATOMIC_RELAXED, __HIP_MEMORY_SCOPE_AGENT);
            if (v < best || (v == best && i < bi)) { best = v; bi = i; }
        }
        const float li = (float)loc[2 * bi];
        const float lj = (float)loc[2 * bi + 1];
        bi_s[t] = li;
        bj_s[t] = lj;
        if (blk == 0) { out[2 * t] = li; out[2 * t + 1] = lj; }
        msum = sqrtf(fmaxf(best, 0.f));
    }
#pragma unroll
    for (int m = 1; m < 64; m <<= 1) msum += __shfl_xor(msum, m);
    if (t < BATCH && (t & 63) == 0) partial[t >> 6] = msum;
    __syncthreads();
    if (blk == 0 && t == 0) out[256] = (partial[0] + partial[1]) * (1.0f / 128.0f);

    const float lr    = lrp[0];
    const float alpha = 0.05f * lr;
    const float sig   = 50.0f * lr;
    const float inv   = 1.0f / (2.0f * sig * sig + 1e-5f);

    const int gl = t & 63;
    const int ch = t >> 6;
    const int g  = blk * 64 + gl;
    const float gi = (float)(g / MCOLS);
    const float gj = (float)(g % MCOLS);

    float acc[DIM];
#pragma unroll
    for (int d = 0; d < DIM; ++d) acc[d] = 0.f;
    float s0 = 0.f;

    const int bbase = ch * 32;
    for (int i = 0; i < 32; ++i) {
        const int bu = __builtin_amdgcn_readfirstlane(bbase + i);  // wave-uniform
        const float dr = gi - bi_s[bu];
        const float dc = gj - bj_s[bu];
        const float w  = alpha * __expf(-fmaf(dr, dr, dc * dc) * inv);
        s0 += w;
        const float4* xrp = (const float4*)(x + (size_t)bu * DIM);
#pragma unroll
        for (int k = 0; k < 8; ++k) {
            float4 xv = xrp[k];
            acc[4*k+0] = fmaf(w, xv.x, acc[4*k+0]);
            acc[4*k+1] = fmaf(w, xv.y, acc[4*k+1]);
            acc[4*k+2] = fmaf(w, xv.z, acc[4*k+2]);
            acc[4*k+3] = fmaf(w, xv.w, acc[4*k+3]);
        }
    }

#pragma unroll
    for (int d = 0; d < DIM; ++d) red[ch][gl][d] = acc[d];
    red[ch][gl][32] = s0;
    __syncthreads();

    const int gl2  = t >> 2;
    const int part = t & 3;
    const int g2   = blk * 64 + gl2;
    if (g2 < GRID_N) {
        const float ssum = red[0][gl2][32] + red[1][gl2][32] +
                           red[2][gl2][32] + red[3][gl2][32];
#pragma unroll
        for (int k = 0; k < 8; ++k) {
            const int d = part * 8 + k;
            const float a  = red[0][gl2][d] + red[1][gl2][d] +
                             red[2][gl2][d] + red[3][gl2][d];
            const float cg = c[(size_t)g2 * DIM + d];
            out[257 + (size_t)g2 * DIM + d] = cg + (a - ssum * cg) * (1.0f / 128.0f);
        }
    }
}

// ---------------------------------------------------------------------------
extern "C" void kernel_launch(void* const* d_in, const int* in_sizes, int n_in,
                              void* d_out, int out_size, void* d_ws, size_t ws_size,
                              hipStream_t stream) {
    const float* x   = (const float*)d_in[0];
    const float* c   = (const float*)d_in[1];
    const int*   loc = (const int*)d_in[2];
    // d_in[3] = distance_mat: recomputed on the fly (exact for integer coords)
    const float* lrp = (const float*)d_in[4];
    float* out = (float*)d_out;

    float* pmin = (float*)d_ws;                        // 1024 floats
    int*   pidx = (int*)((char*)d_ws + 1024 * 4);      // 1024 ints

    void* args[] = { (void*)&x, (void*)&c, (void*)&loc, (void*)&lrp,
                     (void*)&out, (void*)&pmin, (void*)&pidx };
    hipLaunchCooperativeKernel((const void*)som_fused, dim3(NBLK), dim3(256),
                               args, 0, stream);
}

// Round 4
// 51.353 us; speedup vs baseline: 1.0505x; 1.0505x over previous
//
#include <hip/hip_runtime.h>
#include <math.h>

#define BATCH 128
#define GRID_N 10000
#define DIM 32
#define MCOLS 100
#define NCHUNK 8      // g-chunks in phase A
#define GCHUNK 1250   // g's per chunk
#define NBLK 256

// ---------------------------------------------------------------------------
// Fused SOM step, plain launch (256 blocks x 256 threads) with a hand-rolled
// replay-safe barrier: flags[] zeroed by a hipMemsetAsync captured in the
// graph; block i release-stores flags[i]=1 (agent scope) after its partial-BMU
// stores; thread t of every block acquire-polls flags[t]. No cooperative
// launch, no grid.sync.
// Phase A: partial BMU (32 b-groups of 4 rows x 8 g-chunks).
// Phase C (blocks 0..156): per-block argmin finalize + weight update;
// block 0 also writes bmu_loc and mean(mindist).
// ---------------------------------------------------------------------------
__global__ __launch_bounds__(256) void som_fused(
    const float* __restrict__ x, const float* __restrict__ c,
    const int* __restrict__ loc, const float* __restrict__ lrp,
    float* __restrict__ out, float* pmin, int* pidx, unsigned* flags)
{
    const int t   = threadIdx.x;
    const int blk = blockIdx.x;

    __shared__ float sm[4][4];
    __shared__ int   si[4][4];
    __shared__ float bi_s[BATCH], bj_s[BATCH];
    __shared__ float red[4][64][33];
    __shared__ float partial[2];

    // ---------------- Phase A: partial BMU ----------------
    {
        const int bg    = blk >> 3;      // 0..31
        const int chunk = blk & 7;       // 0..7
        const int b0    = bg * 4;

        float xr[4][DIM];
#pragma unroll
        for (int i = 0; i < 4; ++i)
#pragma unroll
            for (int d = 0; d < DIM; ++d)
                xr[i][d] = x[(b0 + i) * DIM + d];

        const int gstart = chunk * GCHUNK;
        float best[4] = {3.4e38f, 3.4e38f, 3.4e38f, 3.4e38f};
        int   idx[4]  = {0, 0, 0, 0};

        for (int g = gstart + t; g < gstart + GCHUNK; g += 256) {
            const float4* cr = (const float4*)(c + (size_t)g * DIM);
            float d2[4] = {0.f, 0.f, 0.f, 0.f};
#pragma unroll
            for (int k = 0; k < 8; ++k) {
                float4 cv = cr[k];
#pragma unroll
                for (int i = 0; i < 4; ++i) {
                    float a;
                    a = xr[i][4*k+0] - cv.x; d2[i] = fmaf(a, a, d2[i]);
                    a = xr[i][4*k+1] - cv.y; d2[i] = fmaf(a, a, d2[i]);
                    a = xr[i][4*k+2] - cv.z; d2[i] = fmaf(a, a, d2[i]);
                    a = xr[i][4*k+3] - cv.w; d2[i] = fmaf(a, a, d2[i]);
                }
            }
#pragma unroll
            for (int i = 0; i < 4; ++i)
                if (d2[i] < best[i]) { best[i] = d2[i]; idx[i] = g; }  // strict <
        }

#pragma unroll
        for (int m = 1; m < 64; m <<= 1) {
#pragma unroll
            for (int i = 0; i < 4; ++i) {
                float o  = __shfl_xor(best[i], m);
                int   oi = __shfl_xor(idx[i], m);
                if (o < best[i] || (o == best[i] && oi < idx[i])) { best[i] = o; idx[i] = oi; }
            }
        }

        const int wave = t >> 6, lane = t & 63;
        if (lane == 0) {
#pragma unroll
            for (int i = 0; i < 4; ++i) { sm[i][wave] = best[i]; si[i][wave] = idx[i]; }
        }
        __syncthreads();
        if (t < 4) {
            float bb = sm[t][0]; int bi = si[t][0];
#pragma unroll
            for (int w = 1; w < 4; ++w)
                if (sm[t][w] < bb || (sm[t][w] == bb && si[t][w] < bi)) { bb = sm[t][w]; bi = si[t][w]; }
            __hip_atomic_store(&pmin[(b0 + t) * NCHUNK + chunk], bb,
                               __ATOMIC_RELAXED, __HIP_MEMORY_SCOPE_AGENT);
            __hip_atomic_store(&pidx[(b0 + t) * NCHUNK + chunk], bi,
                               __ATOMIC_RELAXED, __HIP_MEMORY_SCOPE_AGENT);
        }
    }

    // ---------------- hand-rolled grid barrier ----------------
    __syncthreads();   // all phase-A agent stores of this block issued
    if (t == 0)
        __hip_atomic_store(&flags[blk], 1u, __ATOMIC_RELEASE, __HIP_MEMORY_SCOPE_AGENT);
    // thread t polls flags[t]; 256 threads cover all 256 blocks
    while (__hip_atomic_load(&flags[t], __ATOMIC_ACQUIRE, __HIP_MEMORY_SCOPE_AGENT) == 0u)
        __builtin_amdgcn_s_sleep(1);
    __syncthreads();

    if (blk >= 157) return;

    // ---------------- Phase C: finalize + update ----------------
    float msum = 0.f;
    if (t < BATCH) {
        float best = __hip_atomic_load(&pmin[t * NCHUNK], __ATOMIC_RELAXED, __HIP_MEMORY_SCOPE_AGENT);
        int   bi   = __hip_atomic_load(&pidx[t * NCHUNK], __ATOMIC_RELAXED, __HIP_MEMORY_SCOPE_AGENT);
#pragma unroll
        for (int k = 1; k < NCHUNK; ++k) {
            float v = __hip_atomic_load(&pmin[t * NCHUNK + k], __ATOMIC_RELAXED, __HIP_MEMORY_SCOPE_AGENT);
            int   i = __hip_atomic_load(&pidx[t * NCHUNK + k], __ATOMIC_RELAXED, __HIP_MEMORY_SCOPE_AGENT);
            if (v < best || (v == best && i < bi)) { best = v; bi = i; }
        }
        const float li = (float)loc[2 * bi];
        const float lj = (float)loc[2 * bi + 1];
        bi_s[t] = li;
        bj_s[t] = lj;
        if (blk == 0) { out[2 * t] = li; out[2 * t + 1] = lj; }
        msum = sqrtf(fmaxf(best, 0.f));
    }
#pragma unroll
    for (int m = 1; m < 64; m <<= 1) msum += __shfl_xor(msum, m);
    if (t < BATCH && (t & 63) == 0) partial[t >> 6] = msum;
    __syncthreads();
    if (blk == 0 && t == 0) out[256] = (partial[0] + partial[1]) * (1.0f / 128.0f);

    const float lr    = lrp[0];
    const float alpha = 0.05f * lr;
    const float sig   = 50.0f * lr;
    const float inv   = 1.0f / (2.0f * sig * sig + 1e-5f);

    const int gl = t & 63;
    const int ch = t >> 6;
    const int g  = blk * 64 + gl;
    const float gi = (float)(g / MCOLS);
    const float gj = (float)(g % MCOLS);

    float acc[DIM];
#pragma unroll
    for (int d = 0; d < DIM; ++d) acc[d] = 0.f;
    float s0 = 0.f;

    const int bbase = ch * 32;
    for (int i = 0; i < 32; ++i) {
        const int bu = __builtin_amdgcn_readfirstlane(bbase + i);  // wave-uniform
        const float dr = gi - bi_s[bu];
        const float dc = gj - bj_s[bu];
        const float w  = alpha * __expf(-fmaf(dr, dr, dc * dc) * inv);
        s0 += w;
        const float4* xrp = (const float4*)(x + (size_t)bu * DIM);
#pragma unroll
        for (int k = 0; k < 8; ++k) {
            float4 xv = xrp[k];
            acc[4*k+0] = fmaf(w, xv.x, acc[4*k+0]);
            acc[4*k+1] = fmaf(w, xv.y, acc[4*k+1]);
            acc[4*k+2] = fmaf(w, xv.z, acc[4*k+2]);
            acc[4*k+3] = fmaf(w, xv.w, acc[4*k+3]);
        }
    }

#pragma unroll
    for (int d = 0; d < DIM; ++d) red[ch][gl][d] = acc[d];
    red[ch][gl][32] = s0;
    __syncthreads();

    const int gl2  = t >> 2;
    const int part = t & 3;
    const int g2   = blk * 64 + gl2;
    if (g2 < GRID_N) {
        const float ssum = red[0][gl2][32] + red[1][gl2][32] +
                           red[2][gl2][32] + red[3][gl2][32];
#pragma unroll
        for (int k = 0; k < 8; ++k) {
            const int d = part * 8 + k;
            const float a  = red[0][gl2][d] + red[1][gl2][d] +
                             red[2][gl2][d] + red[3][gl2][d];
            const float cg = c[(size_t)g2 * DIM + d];
            out[257 + (size_t)g2 * DIM + d] = cg + (a - ssum * cg) * (1.0f / 128.0f);
        }
    }
}

// ---------------------------------------------------------------------------
extern "C" void kernel_launch(void* const* d_in, const int* in_sizes, int n_in,
                              void* d_out, int out_size, void* d_ws, size_t ws_size,
                              hipStream_t stream) {
    const float* x   = (const float*)d_in[0];
    const float* c   = (const float*)d_in[1];
    const int*   loc = (const int*)d_in[2];
    // d_in[3] = distance_mat: recomputed on the fly (exact for integer coords)
    const float* lrp = (const float*)d_in[4];
    float* out = (float*)d_out;

    float*    pmin  = (float*)d_ws;                      // 1024 floats
    int*      pidx  = (int*)((char*)d_ws + 1024 * 4);    // 1024 ints
    unsigned* flags = (unsigned*)((char*)d_ws + 2048 * 4); // 256 u32

    // zero the barrier flags every call (captured in the graph, replay-safe)
    hipMemsetAsync(flags, 0, NBLK * sizeof(unsigned), stream);

    hipLaunchKernelGGL(som_fused, dim3(NBLK), dim3(256), 0, stream,
                       x, c, loc, lrp, out, pmin, pidx, flags);
}

// Round 5
// 28.032 us; speedup vs baseline: 1.9244x; 1.8319x over previous
//
#include <hip/hip_runtime.h>
#include <math.h>

#define BATCH 128
#define GRID_N 10000
#define DIM 32
#define MCOLS 100
#define NCHUNK 16     // g-chunks in K1
#define GCHUNK 625    // g's per chunk
#define K1BLK 512
#define K3_GPB 32     // g's per K3 block
#define K3BLK 313     // ceil(10000/32)

// ---------------------------------------------------------------------------
// K1: partial BMU search. 32 b-groups (4 rows of x each) x 16 g-chunks (625)
// = 512 blocks (2/CU), 256 threads. Direct-diff ||x-c||^2, first-index
// tie-break. Writes pmin/pidx[b*16+chunk].
// ---------------------------------------------------------------------------
__global__ __launch_bounds__(256) void k1_bmu(const float* __restrict__ x,
                                              const float* __restrict__ c,
                                              float* __restrict__ pmin,
                                              int* __restrict__ pidx) {
    const int blk   = blockIdx.x;
    const int bg    = blk >> 4;      // 0..31
    const int chunk = blk & 15;      // 0..15
    const int b0    = bg * 4;
    const int t     = threadIdx.x;

    float xr[4][DIM];
#pragma unroll
    for (int i = 0; i < 4; ++i)
#pragma unroll
        for (int d = 0; d < DIM; ++d)
            xr[i][d] = x[(b0 + i) * DIM + d];

    const int gstart = chunk * GCHUNK;
    const int gend   = gstart + GCHUNK;

    float best[4] = {3.4e38f, 3.4e38f, 3.4e38f, 3.4e38f};
    int   idx[4]  = {0, 0, 0, 0};

    for (int g = gstart + t; g < gend; g += 256) {
        const float4* cr = (const float4*)(c + (size_t)g * DIM);
        float d2[4] = {0.f, 0.f, 0.f, 0.f};
#pragma unroll
        for (int k = 0; k < 8; ++k) {
            float4 cv = cr[k];
#pragma unroll
            for (int i = 0; i < 4; ++i) {
                float a;
                a = xr[i][4*k+0] - cv.x; d2[i] = fmaf(a, a, d2[i]);
                a = xr[i][4*k+1] - cv.y; d2[i] = fmaf(a, a, d2[i]);
                a = xr[i][4*k+2] - cv.z; d2[i] = fmaf(a, a, d2[i]);
                a = xr[i][4*k+3] - cv.w; d2[i] = fmaf(a, a, d2[i]);
            }
        }
#pragma unroll
        for (int i = 0; i < 4; ++i)
            if (d2[i] < best[i]) { best[i] = d2[i]; idx[i] = g; }  // strict <: keeps first
    }

    // 64-lane butterfly, min with smallest-index tie-break
#pragma unroll
    for (int m = 1; m < 64; m <<= 1) {
#pragma unroll
        for (int i = 0; i < 4; ++i) {
            float o  = __shfl_xor(best[i], m);
            int   oi = __shfl_xor(idx[i], m);
            if (o < best[i] || (o == best[i] && oi < idx[i])) { best[i] = o; idx[i] = oi; }
        }
    }

    __shared__ float sm[4][4];
    __shared__ int   si[4][4];
    const int wave = t >> 6;
    const int lane = t & 63;
    if (lane == 0) {
#pragma unroll
        for (int i = 0; i < 4; ++i) { sm[i][wave] = best[i]; si[i][wave] = idx[i]; }
    }
    __syncthreads();
    if (t < 4) {
        float bb = sm[t][0]; int bi = si[t][0];
#pragma unroll
        for (int w = 1; w < 4; ++w)
            if (sm[t][w] < bb || (sm[t][w] == bb && si[t][w] < bi)) { bb = sm[t][w]; bi = si[t][w]; }
        pmin[(b0 + t) * NCHUNK + chunk] = bb;
        pidx[(b0 + t) * NCHUNK + chunk] = bi;
    }
}

// ---------------------------------------------------------------------------
// K3: finalize argmin (redundantly per block from L2-hot partials) + weight
// update. 313 blocks x 256 threads; thread = (g_local = t&31, b-chunk =
// t>>5 of 16 rows). Block 0 additionally writes bmu_loc and mean(mindist).
// ---------------------------------------------------------------------------
__global__ __launch_bounds__(256) void k3_update(const float* __restrict__ x,
                                                 const float* __restrict__ c,
                                                 const int* __restrict__ loc,
                                                 const float* __restrict__ pmin,
                                                 const int* __restrict__ pidx,
                                                 const float* __restrict__ lrp,
                                                 float* __restrict__ out) {
    __shared__ float bi_s[BATCH], bj_s[BATCH];
    __shared__ float red[8][K3_GPB][33];
    __shared__ float partial[2];

    const int t = threadIdx.x;

    // ---- finalize per-b argmin over 16 chunks ----
    float msum = 0.f;
    if (t < BATCH) {
        float best = pmin[t * NCHUNK];
        int   bi   = pidx[t * NCHUNK];
#pragma unroll
        for (int k = 1; k < NCHUNK; ++k) {
            float v = pmin[t * NCHUNK + k];
            int   i = pidx[t * NCHUNK + k];
            if (v < best || (v == best && i < bi)) { best = v; bi = i; }
        }
        const float li = (float)loc[2 * bi];
        const float lj = (float)loc[2 * bi + 1];
        bi_s[t] = li;
        bj_s[t] = lj;
        if (blockIdx.x == 0) { out[2 * t] = li; out[2 * t + 1] = lj; }
        msum = sqrtf(fmaxf(best, 0.f));
    }
#pragma unroll
    for (int m = 1; m < 64; m <<= 1) msum += __shfl_xor(msum, m);
    if (t < BATCH && (t & 63) == 0) partial[t >> 6] = msum;
    __syncthreads();
    if (blockIdx.x == 0 && t == 0) out[256] = (partial[0] + partial[1]) * (1.0f / 128.0f);

    // ---- weight update ----
    const float lr    = lrp[0];
    const float alpha = 0.05f * lr;
    const float sig   = 50.0f * lr;
    const float inv   = 1.0f / (2.0f * sig * sig + 1e-5f);

    const int gl = t & 31;           // 0..31
    const int ch = t >> 5;           // 0..7
    const int g  = blockIdx.x * K3_GPB + gl;
    const float gi = (float)(g / MCOLS);
    const float gj = (float)(g % MCOLS);

    float acc[DIM];
#pragma unroll
    for (int d = 0; d < DIM; ++d) acc[d] = 0.f;
    float s0 = 0.f;

    const int bbase = ch * 16;
    for (int i = 0; i < 16; ++i) {
        const int bu = bbase + i;    // wave covers 2 ch values; bu uniform per half-wave
        const float dr = gi - bi_s[bu];
        const float dc = gj - bj_s[bu];
        const float w  = alpha * __expf(-fmaf(dr, dr, dc * dc) * inv);
        s0 += w;
        const float4* xrp = (const float4*)(x + (size_t)bu * DIM);
#pragma unroll
        for (int k = 0; k < 8; ++k) {
            float4 xv = xrp[k];
            acc[4*k+0] = fmaf(w, xv.x, acc[4*k+0]);
            acc[4*k+1] = fmaf(w, xv.y, acc[4*k+1]);
            acc[4*k+2] = fmaf(w, xv.z, acc[4*k+2]);
            acc[4*k+3] = fmaf(w, xv.w, acc[4*k+3]);
        }
    }

#pragma unroll
    for (int d = 0; d < DIM; ++d) red[ch][gl][d] = acc[d];
    red[ch][gl][32] = s0;
    __syncthreads();

    const int gl2  = t >> 3;         // 0..31
    const int part = t & 7;          // 8 parts x 4 d's
    const int g2   = blockIdx.x * K3_GPB + gl2;
    if (g2 < GRID_N) {
        float ssum = 0.f;
#pragma unroll
        for (int w = 0; w < 8; ++w) ssum += red[w][gl2][32];
#pragma unroll
        for (int k = 0; k < 4; ++k) {
            const int d = part * 4 + k;
            float a = 0.f;
#pragma unroll
            for (int w = 0; w < 8; ++w) a += red[w][gl2][d];
            const float cg = c[(size_t)g2 * DIM + d];
            out[257 + (size_t)g2 * DIM + d] = cg + (a - ssum * cg) * (1.0f / 128.0f);
        }
    }
}

// ---------------------------------------------------------------------------
extern "C" void kernel_launch(void* const* d_in, const int* in_sizes, int n_in,
                              void* d_out, int out_size, void* d_ws, size_t ws_size,
                              hipStream_t stream) {
    const float* x   = (const float*)d_in[0];
    const float* c   = (const float*)d_in[1];
    const int*   loc = (const int*)d_in[2];
    // d_in[3] = distance_mat: recomputed on the fly (exact for integer coords)
    const float* lrp = (const float*)d_in[4];
    float* out = (float*)d_out;

    float* pmin = (float*)d_ws;                        // 128*16 floats
    int*   pidx = (int*)((char*)d_ws + 2048 * 4);      // 128*16 ints

    hipLaunchKernelGGL(k1_bmu,    dim3(K1BLK), dim3(256), 0, stream, x, c, pmin, pidx);
    hipLaunchKernelGGL(k3_update, dim3(K3BLK), dim3(256), 0, stream, x, c, loc, pmin, pidx, lrp, out);
}

// Round 6
// 21.650 us; speedup vs baseline: 2.4917x; 1.2948x over previous
//
#include <hip/hip_runtime.h>
#include <math.h>

#define BATCH 128
#define GRID_N 10000
#define DIM 32
#define MCOLS 100
#define NCHUNK 8      // g-chunks in K1
#define GCHUNK 1250   // g's per chunk
#define K1BLK 256
#define K3BLK 157

// ---------------------------------------------------------------------------
// K1: partial BMU search. 32 b-groups (4 rows of x each) x 8 g-chunks (1250)
// = 256 blocks, 512 threads (2 waves/SIMD for L2-latency hiding).
// Direct-diff ||x-c||^2, first-index tie-break. Writes pmin/pidx[b*8+chunk].
// ---------------------------------------------------------------------------
__global__ __launch_bounds__(512) void k1_bmu(const float* __restrict__ x,
                                              const float* __restrict__ c,
                                              float* __restrict__ pmin,
                                              int* __restrict__ pidx) {
    const int blk   = blockIdx.x;
    const int bg    = blk >> 3;      // 0..31
    const int chunk = blk & 7;       // 0..7
    const int b0    = bg * 4;
    const int t     = threadIdx.x;

    float xr[4][DIM];
#pragma unroll
    for (int i = 0; i < 4; ++i)
#pragma unroll
        for (int d = 0; d < DIM; ++d)
            xr[i][d] = x[(b0 + i) * DIM + d];

    const int gstart = chunk * GCHUNK;
    const int gend   = gstart + GCHUNK;

    float best[4] = {3.4e38f, 3.4e38f, 3.4e38f, 3.4e38f};
    int   idx[4]  = {0, 0, 0, 0};

    for (int g = gstart + t; g < gend; g += 512) {
        const float4* cr = (const float4*)(c + (size_t)g * DIM);
        float d2[4] = {0.f, 0.f, 0.f, 0.f};
#pragma unroll
        for (int k = 0; k < 8; ++k) {
            float4 cv = cr[k];
#pragma unroll
            for (int i = 0; i < 4; ++i) {
                float a;
                a = xr[i][4*k+0] - cv.x; d2[i] = fmaf(a, a, d2[i]);
                a = xr[i][4*k+1] - cv.y; d2[i] = fmaf(a, a, d2[i]);
                a = xr[i][4*k+2] - cv.z; d2[i] = fmaf(a, a, d2[i]);
                a = xr[i][4*k+3] - cv.w; d2[i] = fmaf(a, a, d2[i]);
            }
        }
#pragma unroll
        for (int i = 0; i < 4; ++i)
            if (d2[i] < best[i]) { best[i] = d2[i]; idx[i] = g; }  // strict <: keeps first
    }

    // 64-lane butterfly, min with smallest-index tie-break
#pragma unroll
    for (int m = 1; m < 64; m <<= 1) {
#pragma unroll
        for (int i = 0; i < 4; ++i) {
            float o  = __shfl_xor(best[i], m);
            int   oi = __shfl_xor(idx[i], m);
            if (o < best[i] || (o == best[i] && oi < idx[i])) { best[i] = o; idx[i] = oi; }
        }
    }

    __shared__ float sm[4][8];
    __shared__ int   si[4][8];
    const int wave = t >> 6;         // 0..7
    const int lane = t & 63;
    if (lane == 0) {
#pragma unroll
        for (int i = 0; i < 4; ++i) { sm[i][wave] = best[i]; si[i][wave] = idx[i]; }
    }
    __syncthreads();
    if (t < 4) {
        float bb = sm[t][0]; int bi = si[t][0];
#pragma unroll
        for (int w = 1; w < 8; ++w)
            if (sm[t][w] < bb || (sm[t][w] == bb && si[t][w] < bi)) { bb = sm[t][w]; bi = si[t][w]; }
        pmin[(b0 + t) * NCHUNK + chunk] = bb;
        pidx[(b0 + t) * NCHUNK + chunk] = bi;
    }
}

// ---------------------------------------------------------------------------
// K3: finalize argmin (redundantly per block from L2-hot 4KB partials) +
// weight update. 157 blocks x 512 threads; thread = (g_local = t&63,
// b-chunk = t>>6 of 16 rows). Two-pass LDS reduce (chunks 4..7 add into
// 0..3) keeps LDS at 34 KB. Block 0 also writes bmu_loc and mean(mindist).
// ---------------------------------------------------------------------------
__global__ __launch_bounds__(512) void k3_update(const float* __restrict__ x,
                                                 const float* __restrict__ c,
                                                 const int* __restrict__ loc,
                                                 const float* __restrict__ pmin,
                                                 const int* __restrict__ pidx,
                                                 const float* __restrict__ lrp,
                                                 float* __restrict__ out) {
    __shared__ float bi_s[BATCH], bj_s[BATCH];
    __shared__ float red[4][64][33];
    __shared__ float partial[2];

    const int t = threadIdx.x;

    // ---- finalize per-b argmin over 8 chunks ----
    float msum = 0.f;
    if (t < BATCH) {
        float best = pmin[t * NCHUNK];
        int   bi   = pidx[t * NCHUNK];
#pragma unroll
        for (int k = 1; k < NCHUNK; ++k) {
            float v = pmin[t * NCHUNK + k];
            int   i = pidx[t * NCHUNK + k];
            if (v < best || (v == best && i < bi)) { best = v; bi = i; }
        }
        const float li = (float)loc[2 * bi];
        const float lj = (float)loc[2 * bi + 1];
        bi_s[t] = li;
        bj_s[t] = lj;
        if (blockIdx.x == 0) { out[2 * t] = li; out[2 * t + 1] = lj; }
        msum = sqrtf(fmaxf(best, 0.f));
    }
#pragma unroll
    for (int m = 1; m < 64; m <<= 1) msum += __shfl_xor(msum, m);
    if (t < BATCH && (t & 63) == 0) partial[t >> 6] = msum;
    __syncthreads();
    if (blockIdx.x == 0 && t == 0) out[256] = (partial[0] + partial[1]) * (1.0f / 128.0f);

    // ---- weight update ----
    const float lr    = lrp[0];
    const float alpha = 0.05f * lr;
    const float sig   = 50.0f * lr;
    const float inv   = 1.0f / (2.0f * sig * sig + 1e-5f);

    const int gl = t & 63;           // 0..63
    const int ch = t >> 6;           // 0..7 (one wave each)
    const int g  = blockIdx.x * 64 + gl;
    const float gi = (float)(g / MCOLS);
    const float gj = (float)(g % MCOLS);

    float acc[DIM];
#pragma unroll
    for (int d = 0; d < DIM; ++d) acc[d] = 0.f;
    float s0 = 0.f;

    const int bbase = ch * 16;
    for (int i = 0; i < 16; ++i) {
        const int bu = __builtin_amdgcn_readfirstlane(bbase + i);  // wave-uniform
        const float dr = gi - bi_s[bu];
        const float dc = gj - bj_s[bu];
        const float w  = alpha * __expf(-fmaf(dr, dr, dc * dc) * inv);
        s0 += w;
        const float4* xrp = (const float4*)(x + (size_t)bu * DIM);
#pragma unroll
        for (int k = 0; k < 8; ++k) {
            float4 xv = xrp[k];
            acc[4*k+0] = fmaf(w, xv.x, acc[4*k+0]);
            acc[4*k+1] = fmaf(w, xv.y, acc[4*k+1]);
            acc[4*k+2] = fmaf(w, xv.z, acc[4*k+2]);
            acc[4*k+3] = fmaf(w, xv.w, acc[4*k+3]);
        }
    }

    // two-pass reduce: chunks 0..3 write, chunks 4..7 accumulate
    if (ch < 4) {
#pragma unroll
        for (int d = 0; d < DIM; ++d) red[ch][gl][d] = acc[d];
        red[ch][gl][32] = s0;
    }
    __syncthreads();
    if (ch >= 4) {
#pragma unroll
        for (int d = 0; d < DIM; ++d) red[ch - 4][gl][d] += acc[d];
        red[ch - 4][gl][32] += s0;
    }
    __syncthreads();

    const int gl2  = t >> 3;         // 0..63
    const int part = t & 7;          // 8 parts x 4 d's
    const int g2   = blockIdx.x * 64 + gl2;
    if (g2 < GRID_N) {
        float ssum = 0.f;
#pragma unroll
        for (int w = 0; w < 4; ++w) ssum += red[w][gl2][32];
#pragma unroll
        for (int k = 0; k < 4; ++k) {
            const int d = part * 4 + k;
            float a = 0.f;
#pragma unroll
            for (int w = 0; w < 4; ++w) a += red[w][gl2][d];
            const float cg = c[(size_t)g2 * DIM + d];
            out[257 + (size_t)g2 * DIM + d] = cg + (a - ssum * cg) * (1.0f / 128.0f);
        }
    }
}

// ---------------------------------------------------------------------------
extern "C" void kernel_launch(void* const* d_in, const int* in_sizes, int n_in,
                              void* d_out, int out_size, void* d_ws, size_t ws_size,
                              hipStream_t stream) {
    const float* x   = (const float*)d_in[0];
    const float* c   = (const float*)d_in[1];
    const int*   loc = (const int*)d_in[2];
    // d_in[3] = distance_mat: recomputed on the fly (exact for integer coords)
    const float* lrp = (const float*)d_in[4];
    float* out = (float*)d_out;

    float* pmin = (float*)d_ws;                        // 128*8 floats
    int*   pidx = (int*)((char*)d_ws + 1024 * 4);      // 128*8 ints

    hipLaunchKernelGGL(k1_bmu,    dim3(K1BLK), dim3(512), 0, stream, x, c, pmin, pidx);
    hipLaunchKernelGGL(k3_update, dim3(K3BLK), dim3(512), 0, stream, x, c, loc, pmin, pidx, lrp, out);
}